// Round 14
// baseline (163.224 us; speedup 1.0000x reference)
//
#include <hip/hip_runtime.h>
#include <hip/hip_bf16.h>
#include <hip/hip_fp16.h>
#include <math.h>

// LGCN layer, R28 = R27 + srf phase-3 node-PAIRING (32 edges in flight) +
// scatter atomic/store batch split.
// R27 post-mortem: 155.4us (best); fill (~45.5us) is the top dispatch; both
// kernels <44.3. srf phase 3 walked 8 nodes sequentially -- ~2 quad-iters
// per node means the 16-edge pipeline never fills before the 12-shuffle
// epilogue drains it. This round: process node pairs jointly (one loop over
// max(lenA,lenB), per-quad predication, invalid slots masked to src=0/att=0
// so every FWh access stays in-bounds) -> 8 ds_read + 8 vmem per iter = 32
// edges in flight, half the latency-exposed trips. Scatter: issue the 4 LDS
// atomic-returns before the 4 stores (overlap the atomic latencies).
// JOURNAL RULES:
//   - scatter stores must be >=1-line runs (R26: per-node 4B slots = 16x
//     write amp, 130us).
//   - LDS FP atomicAdd = CAS loop (R19, 684us).
//   - per-edge scalar math must be thread-parallel (R23, 32x redundancy).
//   - harness fillBuffer (256MiB re-poison) is a fixed ~46us floor.

#define D 64
#define SHIFT 6
#define NB (1 << SHIFT)          // dst nodes per bucket (64)
#define SCM 1024                 // scatter LDS table size (C=782 <= 1024)
#define CAPB 2560                // fixed slot capacity per bucket (mean+11s)
#define NPW 8                    // nodes per wave in reducer (64 / 8 waves)

typedef _Float16 half8 __attribute__((ext_vector_type(8)));
typedef float f32x4 __attribute__((ext_vector_type(4)));

// ---- kernel 1: [FW|s1|s2] GEMM + WT build + 4B edge scatter (fused) -------
// mfma_f32_16x16x32_f16 layouts (m89-verified): A lane l: row=l&15,
// k=(l>>4)*8+j; B lane l: col=l&15, k=(l>>4)*8+j; C/D: col=l&15,
// row=(l>>4)*4+reg.
// Scatter entry: src | dl<<26 (dl = dst & 63), 4 bytes. No attention here.
__global__ __launch_bounds__(512) void pre_scatter(
    const float* __restrict__ feat, const float* __restrict__ W_rel,
    const float* __restrict__ lin_w, const float* __restrict__ lin_b,
    const float* __restrict__ loop_w, const float* __restrict__ evolve_w,
    const int* __restrict__ esrc, const int* __restrict__ edst,
    float* __restrict__ s1, float* __restrict__ s2, __half* __restrict__ FWh,
    __half* __restrict__ WT, int* __restrict__ gcur,
    unsigned* __restrict__ ebuf, int N, int E, int C) {
  __shared__ int h[SCM];
  __shared__ int cur[SCM];
  __shared__ int bl[SCM];
  for (int i = threadIdx.x; i < C; i += 512) h[i] = 0;
  // no barrier yet: GEMM below doesn't touch h; the barrier before the hist
  // atomics orders init vs use.

  // WT layout: [c192][k], c192 = m*64 + c, m in {0:W_rel, 1:loop, 2:evolve};
  // WT[c192*64 + k] = W_m[k][c]. (srf uses rows 64..191.)
  if (blockIdx.x == 0) {
    for (int i = threadIdx.x; i < 192 * 64; i += 512) {
      const int c192 = i >> 6, k = i & 63;
      const int m = c192 >> 6, c = c192 & 63;
      const float* Wm = (m == 0) ? W_rel : (m == 1) ? loop_w : evolve_w;
      WT[i] = __float2half(Wm[k * 64 + c]);
    }
  }

  // ---- GEMM: 16 rows per wave, 8 waves -> 128 rows/block (blocks 0..390) --
  const int lane = threadIdx.x & 63;
  const int w    = threadIdx.x >> 6;
  const int r    = lane & 15;          // A row within tile / C col
  const int g    = lane >> 4;          // k-group
  const int m0   = (blockIdx.x * 8 + w) * 16;
  if (m0 < N) {
    half8 bw[4][2];
    half8 ba[2];
    #pragma unroll
    for (int ks = 0; ks < 2; ++ks) {
      #pragma unroll
      for (int j = 0; j < 8; ++j) {
        const int k = ks * 32 + g * 8 + j;
        #pragma unroll
        for (int nt = 0; nt < 4; ++nt)
          bw[nt][ks][j] = (_Float16)W_rel[k * 64 + nt * 16 + r];
        const float av = (r == 0) ? lin_w[k] : (r == 1) ? lin_w[64 + k] : 0.0f;
        ba[ks][j] = (_Float16)av;
      }
    }

    // A frags, hi/lo split so hi+lo == feat to ~2^-22
    half8 ah[2], al[2];
    const int arow = m0 + r;
    #pragma unroll
    for (int ks = 0; ks < 2; ++ks) {
      float v[8];
      if (arow < N) {
        const float4 u0 = *(const float4*)&feat[(size_t)arow * D + ks * 32 + g * 8];
        const float4 u1 = *(const float4*)&feat[(size_t)arow * D + ks * 32 + g * 8 + 4];
        v[0] = u0.x; v[1] = u0.y; v[2] = u0.z; v[3] = u0.w;
        v[4] = u1.x; v[5] = u1.y; v[6] = u1.z; v[7] = u1.w;
      } else {
        #pragma unroll
        for (int q = 0; q < 8; ++q) v[q] = 0.0f;
      }
      #pragma unroll
      for (int q = 0; q < 8; ++q) {
        const _Float16 hh = (_Float16)v[q];
        ah[ks][q] = hh;
        al[ks][q] = (_Float16)(v[q] - (float)hh);
      }
    }

    #pragma unroll
    for (int nt = 0; nt < 4; ++nt) {
      f32x4 acc = {0.0f, 0.0f, 0.0f, 0.0f};
      #pragma unroll
      for (int ks = 0; ks < 2; ++ks) {
        acc = __builtin_amdgcn_mfma_f32_16x16x32_f16(ah[ks], bw[nt][ks], acc, 0, 0, 0);
        acc = __builtin_amdgcn_mfma_f32_16x16x32_f16(al[ks], bw[nt][ks], acc, 0, 0, 0);
      }
      #pragma unroll
      for (int q = 0; q < 4; ++q) {
        const int n = m0 + g * 4 + q;
        if (n < N) FWh[(size_t)n * D + nt * 16 + r] = __float2half(acc[q]);
      }
    }

    f32x4 acc5 = {0.0f, 0.0f, 0.0f, 0.0f};   // cols: 0 = s1, 1 = s2
    #pragma unroll
    for (int ks = 0; ks < 2; ++ks) {
      acc5 = __builtin_amdgcn_mfma_f32_16x16x32_f16(ah[ks], ba[ks], acc5, 0, 0, 0);
      acc5 = __builtin_amdgcn_mfma_f32_16x16x32_f16(al[ks], ba[ks], acc5, 0, 0, 0);
    }
    if (r < 2) {
      const float b = lin_b[0];
      #pragma unroll
      for (int q = 0; q < 4; ++q) {
        const int n = m0 + g * 4 + q;
        if (n < N) {
          if (r == 0) s1[n] = acc5[q] + b;
          else        s2[n] = acc5[q];
        }
      }
    }
  }

  __syncthreads();   // h init visible; GEMM waves done

  // ---- scatter: hist -> reserve -> write (4B entries) ----
  const int E4 = E >> 2;
  const int4* edst4 = (const int4*)edst;
  const int4* esrc4 = (const int4*)esrc;
  const int i4 = blockIdx.x * 512 + threadIdx.x;   // one int4 per thread
  const bool tail0 = (blockIdx.x == 0) && (threadIdx.x == 0);

  if (i4 < E4) {
    const int4 d = edst4[i4];
    atomicAdd(&h[d.x >> SHIFT], 1);
    atomicAdd(&h[d.y >> SHIFT], 1);
    atomicAdd(&h[d.z >> SHIFT], 1);
    atomicAdd(&h[d.w >> SHIFT], 1);
  }
  if (tail0) for (int e = E4 << 2; e < E; ++e) atomicAdd(&h[edst[e] >> SHIFT], 1);
  __syncthreads();
  for (int i = threadIdx.x; i < C; i += 512) {
    const int v = h[i];
    bl[i] = v ? atomicAdd(&gcur[i], v) : 0;   // offset within bucket
    cur[i] = 0;
  }
  __syncthreads();

  if (i4 < E4) {
    const int4 s = esrc4[i4];
    const int4 d = edst4[i4];
    const int ss[4] = {s.x, s.y, s.z, s.w};
    const int dd[4] = {d.x, d.y, d.z, d.w};
    int bk[4], rr[4];
    #pragma unroll
    for (int j = 0; j < 4; ++j) bk[j] = dd[j] >> SHIFT;
    #pragma unroll
    for (int j = 0; j < 4; ++j) rr[j] = atomicAdd(&cur[bk[j]], 1);  // overlap
    #pragma unroll
    for (int j = 0; j < 4; ++j) {
      ebuf[(size_t)bk[j] * CAPB + bl[bk[j]] + rr[j]] =
          (unsigned)ss[j] | ((unsigned)(dd[j] & (NB - 1)) << 26);
    }
  }
  if (tail0) {
    for (int e = E4 << 2; e < E; ++e) {
      const int bk = edst[e] >> SHIFT;
      const int rr = atomicAdd(&cur[bk], 1);
      ebuf[(size_t)bk * CAPB + bl[bk] + rr] =
          (unsigned)esrc[e] | ((unsigned)(edst[e] & (NB - 1)) << 26);
    }
  }
}

// -------- kernel 2: sort(+att) + Y-MFMA + PAIRED quad-gather + finalize -----
// One block per bucket (64 nodes, 8 waves of 512 threads). R20 phase order.
//  phase 1: reg-stage 4B entries + LDS hist (INT atomics only); THREAD-
//           PARALLEL attention per staged entry; scan; place uint2{src|dl,att}
//  phase 2: Y = feat @ (loop|evolve) via MFMA -> Yl. Waves 0-3 loop own hm
//           rows; waves 4-7 evolve own !hm rows; evolve skips all-hm tiles.
//  phase 3: PAIRED quad-gather: nodes (2j,2j+1) jointly; per iter 8 ds_read
//           + 8 vmem = 32 edges in flight; invalid slots masked src=0/att=0
//           (all FWh accesses in-bounds); shfl_xor(16,32) + 4-shfl per node.
//  phase 4: out = tanh((hm ? agg : feat) * norm + Yl)
__global__ __launch_bounds__(512, 4) void sort_reduce_finalize(
    const float* __restrict__ feat, const __half* __restrict__ FWh,
    const __half* __restrict__ WT, const float* __restrict__ norm,
    const float* __restrict__ s1, const float* __restrict__ s2,
    const int* __restrict__ gcur, const unsigned* __restrict__ ebuf,
    float* __restrict__ out, int C, int N) {
  __shared__ uint2 sdata[CAPB];         // 20.0 KB
  __shared__ float Yl[NB * D];          // 16 KB
  __shared__ float s2l[NB];
  __shared__ int hist[NB];
  __shared__ int starts[NB + 1];
  __shared__ int roff[NB];

  const int tid  = threadIdx.x;
  const int lane = tid & 63;
  const int w    = tid >> 6;           // 0..7
  const int b    = blockIdx.x;
  const int n0   = b << SHIFT;
  const int beg  = b * CAPB;
  const int cnt  = min(gcur[b], CAPB);

  if (tid < NB) {
    hist[tid] = 0;
    const int n = n0 + tid;
    s2l[tid] = (n < N) ? s2[n] : 0.0f;
  }
  __syncthreads();

  // ---- phase 1: stage + hist + thread-parallel attention + scan + place ----
  unsigned ereg[5];                     // ceil(CAPB/512) = 5
  float    areg[5];
  #pragma unroll
  for (int k = 0; k < 5; ++k) {
    const int i = tid + (k << 9);
    if (i < cnt) {
      ereg[k] = ebuf[beg + i];
      atomicAdd(&hist[ereg[k] >> 26], 1);
    }
  }
  #pragma unroll
  for (int k = 0; k < 5; ++k) {         // att: 64 edges per wave-instr
    const int i = tid + (k << 9);
    if (i < cnt) {
      const unsigned src = ereg[k] & 0x03FFFFFFu;
      const float v = s1[src] + s2l[ereg[k] >> 26];
      areg[k] = 1.0f / (1.0f + __expf(-fmaxf(v, 0.0f)));
    }
  }
  __syncthreads();
  if (tid < 64) {                       // wave 0: scan 64 counters
    const int v = hist[tid];
    int incl = v;
    #pragma unroll
    for (int off = 1; off < 64; off <<= 1) {
      const int o = __shfl_up(incl, off, 64);
      if (tid >= off) incl += o;
    }
    starts[tid] = incl - v;
    roff[tid]   = incl - v;
    if (tid == 63) starts[64] = incl;
  }
  __syncthreads();
  #pragma unroll
  for (int k = 0; k < 5; ++k) {
    const int i = tid + (k << 9);
    if (i < cnt) {
      const int pos = atomicAdd(&roff[ereg[k] >> 26], 1);
      sdata[pos] = make_uint2(ereg[k], __float_as_uint(areg[k]));
    }
  }

  // ---- phase 2: Y = feat @ (loop|evolve) via MFMA -> Yl ----
  {
    const int r = lane & 15, g = lane >> 4;
    const bool evw = (w >= 4);
    const int mt = w & 3;              // row tile: rows mt*16 .. mt*16+15
    bool skip = false;
    if (evw) {                         // skip when all 16 rows have messages
      const int rr0 = mt * 16;
      const int flag = (lane < 16)
          ? ((starts[rr0 + lane + 1] > starts[rr0 + lane]) ? 1 : 0) : 1;
      skip = (__ballot(flag == 0) == 0ULL);
    }
    if (!skip) {
      half8 ah[2], al[2];
      const int arow = n0 + mt * 16 + r;
      #pragma unroll
      for (int ks = 0; ks < 2; ++ks) {
        float v[8];
        if (arow < N) {
          const float4 u0 = *(const float4*)&feat[(size_t)arow * D + ks * 32 + g * 8];
          const float4 u1 = *(const float4*)&feat[(size_t)arow * D + ks * 32 + g * 8 + 4];
          v[0] = u0.x; v[1] = u0.y; v[2] = u0.z; v[3] = u0.w;
          v[4] = u1.x; v[5] = u1.y; v[6] = u1.z; v[7] = u1.w;
        } else {
          #pragma unroll
          for (int q = 0; q < 8; ++q) v[q] = 0.0f;
        }
        #pragma unroll
        for (int q = 0; q < 8; ++q) {
          const _Float16 hh = (_Float16)v[q];
          ah[ks][q] = hh;
          al[ks][q] = (_Float16)(v[q] - (float)hh);
        }
      }
      const int wrow0 = evw ? 128 : 64;  // WT rows: 64=loop, 128=evolve
      #pragma unroll
      for (int nt = 0; nt < 4; ++nt) {
        f32x4 a0 = {0.0f, 0.0f, 0.0f, 0.0f};
        #pragma unroll
        for (int ks = 0; ks < 2; ++ks) {
          const half8 bw = *reinterpret_cast<const half8*>(
              WT + (size_t)(wrow0 + nt * 16 + r) * 64 + ks * 32 + g * 8);
          a0 = __builtin_amdgcn_mfma_f32_16x16x32_f16(ah[ks], bw, a0, 0, 0, 0);
          a0 = __builtin_amdgcn_mfma_f32_16x16x32_f16(al[ks], bw, a0, 0, 0, 0);
        }
        #pragma unroll
        for (int q = 0; q < 4; ++q) {
          const int gr = mt * 16 + g * 4 + q;     // C/D row
          const bool hm = starts[gr + 1] > starts[gr];
          if (evw != hm) Yl[gr * D + nt * 16 + r] = a0[q];  // owner writes
        }
      }
    }
  }
  __syncthreads();   // sdata sorted (with att), Yl ready

  // ---- phase 3: paired quad-gather (2 nodes, 32 edges in flight) ----
  const int qe = lane >> 4;            // edge slot 0..3
  const int qc = lane & 15;            // col group: cols 4qc .. 4qc+3
  float agg[NPW];
  #pragma unroll
  for (int j = 0; j < NPW; ++j) agg[j] = 0.0f;
  for (int j2 = 0; j2 < NPW; j2 += 2) {
    const int dlA = w * NPW + j2;
    const int dlB = dlA + 1;
    const int rbA = __builtin_amdgcn_readfirstlane(starts[dlA]);
    const int reA = __builtin_amdgcn_readfirstlane(starts[dlA + 1]);
    const int rbB = __builtin_amdgcn_readfirstlane(starts[dlB]);
    const int reB = __builtin_amdgcn_readfirstlane(starts[dlB + 1]);
    const int len = max(reA - rbA, reB - rbB);
    float Aa = 0.f, Ab = 0.f, Ac = 0.f, Ad = 0.f;   // node A cols 4qc..+3
    float Ba = 0.f, Bb = 0.f, Bc = 0.f, Bd = 0.f;   // node B
    for (int p = 0; p < len; p += 16) {
      unsigned sA[4], sB[4];
      float    aA[4], aB[4];
      #pragma unroll
      for (int q = 0; q < 4; ++q) {                 // 8 ds_read_b64
        const int ia = rbA + p + 4 * q + qe;
        const int ib = rbB + p + 4 * q + qe;
        const bool va = ia < reA;
        const bool vb = ib < reB;
        const uint2 ea = sdata[va ? ia : 0];        // always in-LDS
        const uint2 eb = sdata[vb ? ib : 0];
        sA[q] = va ? (ea.x & 0x03FFFFFFu) : 0u;     // masked: FWh[0] safe
        sB[q] = vb ? (eb.x & 0x03FFFFFFu) : 0u;
        aA[q] = va ? __uint_as_float(ea.y) : 0.0f;
        aB[q] = vb ? __uint_as_float(eb.y) : 0.0f;
      }
      #pragma unroll
      for (int q = 0; q < 4; ++q) {                 // 8 vmem, 32 edges in flight
        const uint2 wa = *(const uint2*)(FWh + (((size_t)sA[q]) << 6) + (qc << 2));
        const uint2 wb = *(const uint2*)(FWh + (((size_t)sB[q]) << 6) + (qc << 2));
        const float2 fa0 = __half22float2(*(const __half2*)&wa.x);
        const float2 fa1 = __half22float2(*(const __half2*)&wa.y);
        const float2 fb0 = __half22float2(*(const __half2*)&wb.x);
        const float2 fb1 = __half22float2(*(const __half2*)&wb.y);
        Aa += aA[q] * fa0.x; Ab += aA[q] * fa0.y;
        Ac += aA[q] * fa1.x; Ad += aA[q] * fa1.y;
        Ba += aB[q] * fb0.x; Bb += aB[q] * fb0.y;
        Bc += aB[q] * fb1.x; Bd += aB[q] * fb1.y;
      }
    }
    // combine edge slots (lanes differing in bits 4,5)
    Aa += __shfl_xor(Aa, 16, 64); Aa += __shfl_xor(Aa, 32, 64);
    Ab += __shfl_xor(Ab, 16, 64); Ab += __shfl_xor(Ab, 32, 64);
    Ac += __shfl_xor(Ac, 16, 64); Ac += __shfl_xor(Ac, 32, 64);
    Ad += __shfl_xor(Ad, 16, 64); Ad += __shfl_xor(Ad, 32, 64);
    Ba += __shfl_xor(Ba, 16, 64); Ba += __shfl_xor(Ba, 32, 64);
    Bb += __shfl_xor(Bb, 16, 64); Bb += __shfl_xor(Bb, 32, 64);
    Bc += __shfl_xor(Bc, 16, 64); Bc += __shfl_xor(Bc, 32, 64);
    Bd += __shfl_xor(Bd, 16, 64); Bd += __shfl_xor(Bd, 32, 64);
    // redistribute: lane c wants col c = 4*(c>>2) + (c&3); source lane c>>2
    {
      const int srcl = lane >> 2;
      const int sel = lane & 3;
      const float tA0 = __shfl(Aa, srcl, 64);
      const float tA1 = __shfl(Ab, srcl, 64);
      const float tA2 = __shfl(Ac, srcl, 64);
      const float tA3 = __shfl(Ad, srcl, 64);
      agg[j2] = (sel == 0) ? tA0 : (sel == 1) ? tA1 : (sel == 2) ? tA2 : tA3;
      const float tB0 = __shfl(Ba, srcl, 64);
      const float tB1 = __shfl(Bb, srcl, 64);
      const float tB2 = __shfl(Bc, srcl, 64);
      const float tB3 = __shfl(Bd, srcl, 64);
      agg[j2 + 1] = (sel == 0) ? tB0 : (sel == 1) ? tB1 : (sel == 2) ? tB2 : tB3;
    }
  }

  // ---- phase 4: finalize (same (w,j,lane) map as phase 3) ----
  for (int j = 0; j < NPW; ++j) {
    const int dl = w * NPW + j;
    const int n  = n0 + dl;
    if (n >= N) break;
    const bool hm = starts[dl + 1] > starts[dl];   // wave-uniform
    const float nr = norm[n];
    const float base = hm ? agg[j] : feat[(size_t)n * D + lane];
    out[(size_t)n * D + lane] = tanhf(base * nr + Yl[dl * D + lane]);
  }
}

extern "C" void kernel_launch(void* const* d_in, const int* in_sizes, int n_in,
                              void* d_out, int out_size, void* d_ws, size_t ws_size,
                              hipStream_t stream) {
  const float* feat     = (const float*)d_in[0];
  const float* norm     = (const float*)d_in[1];
  const int*   esrc     = (const int*)d_in[2];
  const int*   edst     = (const int*)d_in[3];
  // d_in[4] = etype: no-op permutation per the reference
  const float* W_rel    = (const float*)d_in[5];
  const float* lin_w    = (const float*)d_in[6];
  const float* lin_b    = (const float*)d_in[7];
  const float* loop_w   = (const float*)d_in[8];
  const float* evolve_w = (const float*)d_in[9];
  float* out = (float*)d_out;

  const int N = in_sizes[1];   // norm is [N]   (N <= 65536: src fits 26 bits)
  const int E = in_sizes[2];   // edge_src is [E]
  const int C = (N + NB - 1) >> SHIFT;   // 782 for N=50000

  // layout: s1|s2 | gcur | WT | FWh | ebuf[C*CAPB] 4B  (~15 MB; ws is 256 MiB)
  char* p = (char*)d_ws;
  float*    s1   = (float*)p;    p += (size_t)N * sizeof(float);
  float*    s2   = (float*)p;    p += (size_t)N * sizeof(float);
  int*      gcur = (int*)p;      p += (size_t)2048 * sizeof(int);
  __half*   WT   = (__half*)p;   p += (size_t)192 * 64 * sizeof(__half);
  __half*   FWh  = (__half*)p;   p += (size_t)N * D * sizeof(__half);
  unsigned* ebuf = (unsigned*)p;

  const int E4 = E >> 2;
  const int eblocks = (E4 + 511) / 512;            // 782 for E=1.6M

  hipMemsetAsync(gcur, 0, (size_t)C * sizeof(int), stream);
  pre_scatter<<<eblocks, 512, 0, stream>>>(feat, W_rel, lin_w, lin_b,
                                           loop_w, evolve_w, esrc, edst,
                                           s1, s2, FWh, WT, gcur, ebuf,
                                           N, E, C);
  sort_reduce_finalize<<<C, 512, 0, stream>>>(feat, FWh, WT, norm, s1, s2,
                                              gcur, ebuf, out, C, N);
}

// Round 15
// 153.294 us; speedup vs baseline: 1.0648x; 1.0648x over previous
//
#include <hip/hip_runtime.h>
#include <hip/hip_bf16.h>
#include <hip/hip_fp16.h>
#include <math.h>

// LGCN layer, R29 = revert to R27 (measured best, 155.4us).
// R28 post-mortem: node-pairing regressed srf 41->53.7us: VGPR 32->48
// (occupancy 40->27%), FETCH +6MB (max(lenA,lenB) loop + masked loads still
// issue), VALU +7% (predication). Phase-3 MLP tricks are 1-for-4; srf sits
// at a latency/occupancy equilibrium. JOURNAL RULES:
//   - scatter stores must be >=1-line runs (R26: per-node 4B slots = 16x amp).
//   - LDS FP atomicAdd = CAS loop (R19, 684us).
//   - per-edge scalar math must be thread-parallel (R23, 32x redundancy).
//   - per-wave MLP tricks that add VGPR/predication lose to occupancy (R28).
//   - harness fillBuffer (256MiB re-poison) is a fixed ~46us floor.
// Structure:
//   - pre_scatter: merged GEMM [FW|s1|s2] + WT build + 4B-entry bucketed
//     scatter (LDS hist -> one global reserve atomic per touched bucket ->
//     contiguous runs at ebuf[bk*CAPB...]).
//   - srf: stage+thread-parallel att -> scan -> place -> Y-MFMA -> QUAD-
//     gather (1 vmem + 1 ds per 4 edges, 16 edges in flight) -> finalize.

#define D 64
#define SHIFT 6
#define NB (1 << SHIFT)          // dst nodes per bucket (64)
#define SCM 1024                 // scatter LDS table size (C=782 <= 1024)
#define CAPB 2560                // fixed slot capacity per bucket (mean+11s)
#define NPW 8                    // nodes per wave in reducer (64 / 8 waves)

typedef _Float16 half8 __attribute__((ext_vector_type(8)));
typedef float f32x4 __attribute__((ext_vector_type(4)));

// ---- kernel 1: [FW|s1|s2] GEMM + WT build + 4B edge scatter (fused) -------
// mfma_f32_16x16x32_f16 layouts (m89-verified): A lane l: row=l&15,
// k=(l>>4)*8+j; B lane l: col=l&15, k=(l>>4)*8+j; C/D: col=l&15,
// row=(l>>4)*4+reg.
// Scatter entry: src | dl<<26 (dl = dst & 63), 4 bytes. No attention here.
__global__ __launch_bounds__(512) void pre_scatter(
    const float* __restrict__ feat, const float* __restrict__ W_rel,
    const float* __restrict__ lin_w, const float* __restrict__ lin_b,
    const float* __restrict__ loop_w, const float* __restrict__ evolve_w,
    const int* __restrict__ esrc, const int* __restrict__ edst,
    float* __restrict__ s1, float* __restrict__ s2, __half* __restrict__ FWh,
    __half* __restrict__ WT, int* __restrict__ gcur,
    unsigned* __restrict__ ebuf, int N, int E, int C) {
  __shared__ int h[SCM];
  __shared__ int cur[SCM];
  __shared__ int bl[SCM];
  for (int i = threadIdx.x; i < C; i += 512) h[i] = 0;
  // no barrier yet: GEMM below doesn't touch h; the barrier before the hist
  // atomics orders init vs use.

  // WT layout: [c192][k], c192 = m*64 + c, m in {0:W_rel, 1:loop, 2:evolve};
  // WT[c192*64 + k] = W_m[k][c]. (srf uses rows 64..191.)
  if (blockIdx.x == 0) {
    for (int i = threadIdx.x; i < 192 * 64; i += 512) {
      const int c192 = i >> 6, k = i & 63;
      const int m = c192 >> 6, c = c192 & 63;
      const float* Wm = (m == 0) ? W_rel : (m == 1) ? loop_w : evolve_w;
      WT[i] = __float2half(Wm[k * 64 + c]);
    }
  }

  // ---- GEMM: 16 rows per wave, 8 waves -> 128 rows/block (blocks 0..390) --
  const int lane = threadIdx.x & 63;
  const int w    = threadIdx.x >> 6;
  const int r    = lane & 15;          // A row within tile / C col
  const int g    = lane >> 4;          // k-group
  const int m0   = (blockIdx.x * 8 + w) * 16;
  if (m0 < N) {
    half8 bw[4][2];
    half8 ba[2];
    #pragma unroll
    for (int ks = 0; ks < 2; ++ks) {
      #pragma unroll
      for (int j = 0; j < 8; ++j) {
        const int k = ks * 32 + g * 8 + j;
        #pragma unroll
        for (int nt = 0; nt < 4; ++nt)
          bw[nt][ks][j] = (_Float16)W_rel[k * 64 + nt * 16 + r];
        const float av = (r == 0) ? lin_w[k] : (r == 1) ? lin_w[64 + k] : 0.0f;
        ba[ks][j] = (_Float16)av;
      }
    }

    // A frags, hi/lo split so hi+lo == feat to ~2^-22
    half8 ah[2], al[2];
    const int arow = m0 + r;
    #pragma unroll
    for (int ks = 0; ks < 2; ++ks) {
      float v[8];
      if (arow < N) {
        const float4 u0 = *(const float4*)&feat[(size_t)arow * D + ks * 32 + g * 8];
        const float4 u1 = *(const float4*)&feat[(size_t)arow * D + ks * 32 + g * 8 + 4];
        v[0] = u0.x; v[1] = u0.y; v[2] = u0.z; v[3] = u0.w;
        v[4] = u1.x; v[5] = u1.y; v[6] = u1.z; v[7] = u1.w;
      } else {
        #pragma unroll
        for (int q = 0; q < 8; ++q) v[q] = 0.0f;
      }
      #pragma unroll
      for (int q = 0; q < 8; ++q) {
        const _Float16 hh = (_Float16)v[q];
        ah[ks][q] = hh;
        al[ks][q] = (_Float16)(v[q] - (float)hh);
      }
    }

    #pragma unroll
    for (int nt = 0; nt < 4; ++nt) {
      f32x4 acc = {0.0f, 0.0f, 0.0f, 0.0f};
      #pragma unroll
      for (int ks = 0; ks < 2; ++ks) {
        acc = __builtin_amdgcn_mfma_f32_16x16x32_f16(ah[ks], bw[nt][ks], acc, 0, 0, 0);
        acc = __builtin_amdgcn_mfma_f32_16x16x32_f16(al[ks], bw[nt][ks], acc, 0, 0, 0);
      }
      #pragma unroll
      for (int q = 0; q < 4; ++q) {
        const int n = m0 + g * 4 + q;
        if (n < N) FWh[(size_t)n * D + nt * 16 + r] = __float2half(acc[q]);
      }
    }

    f32x4 acc5 = {0.0f, 0.0f, 0.0f, 0.0f};   // cols: 0 = s1, 1 = s2
    #pragma unroll
    for (int ks = 0; ks < 2; ++ks) {
      acc5 = __builtin_amdgcn_mfma_f32_16x16x32_f16(ah[ks], ba[ks], acc5, 0, 0, 0);
      acc5 = __builtin_amdgcn_mfma_f32_16x16x32_f16(al[ks], ba[ks], acc5, 0, 0, 0);
    }
    if (r < 2) {
      const float b = lin_b[0];
      #pragma unroll
      for (int q = 0; q < 4; ++q) {
        const int n = m0 + g * 4 + q;
        if (n < N) {
          if (r == 0) s1[n] = acc5[q] + b;
          else        s2[n] = acc5[q];
        }
      }
    }
  }

  __syncthreads();   // h init visible; GEMM waves done

  // ---- scatter: hist -> reserve -> write (4B entries) ----
  const int E4 = E >> 2;
  const int4* edst4 = (const int4*)edst;
  const int4* esrc4 = (const int4*)esrc;
  const int i4 = blockIdx.x * 512 + threadIdx.x;   // one int4 per thread
  const bool tail0 = (blockIdx.x == 0) && (threadIdx.x == 0);

  if (i4 < E4) {
    const int4 d = edst4[i4];
    atomicAdd(&h[d.x >> SHIFT], 1);
    atomicAdd(&h[d.y >> SHIFT], 1);
    atomicAdd(&h[d.z >> SHIFT], 1);
    atomicAdd(&h[d.w >> SHIFT], 1);
  }
  if (tail0) for (int e = E4 << 2; e < E; ++e) atomicAdd(&h[edst[e] >> SHIFT], 1);
  __syncthreads();
  for (int i = threadIdx.x; i < C; i += 512) {
    const int v = h[i];
    bl[i] = v ? atomicAdd(&gcur[i], v) : 0;   // offset within bucket
    cur[i] = 0;
  }
  __syncthreads();

  if (i4 < E4) {
    const int4 s = esrc4[i4];
    const int4 d = edst4[i4];
    const int ss[4] = {s.x, s.y, s.z, s.w};
    const int dd[4] = {d.x, d.y, d.z, d.w};
    #pragma unroll
    for (int j = 0; j < 4; ++j) {
      const int bk = dd[j] >> SHIFT;
      const int rr = atomicAdd(&cur[bk], 1);
      ebuf[(size_t)bk * CAPB + bl[bk] + rr] =
          (unsigned)ss[j] | ((unsigned)(dd[j] & (NB - 1)) << 26);
    }
  }
  if (tail0) {
    for (int e = E4 << 2; e < E; ++e) {
      const int bk = edst[e] >> SHIFT;
      const int rr = atomicAdd(&cur[bk], 1);
      ebuf[(size_t)bk * CAPB + bl[bk] + rr] =
          (unsigned)esrc[e] | ((unsigned)(edst[e] & (NB - 1)) << 26);
    }
  }
}

// -------- kernel 2: sort(+att) + Y-MFMA + QUAD-gather reduce + finalize -----
// One block per bucket (64 nodes, 8 waves of 512 threads). R20 phase order.
//  phase 1: reg-stage 4B entries + LDS hist (INT atomics only); THREAD-
//           PARALLEL attention per staged entry; scan; place uint2{src|dl,att}
//  phase 2: Y = feat @ (loop|evolve) via MFMA -> Yl. Waves 0-3 loop own hm
//           rows; waves 4-7 evolve own !hm rows; evolve skips all-hm tiles.
//  phase 3: quad-gather: lane = 16*qe + qc; edge slot qe in [0,4), col group
//           qc covers cols 4qc..4qc+3 (uint2 = 8B); 1 vmem + 1 ds per 4
//           edges; per-node shfl_xor(16,32) + 4-shfl redistribute.
//  phase 4: out = tanh((hm ? agg : feat) * norm + Yl)
__global__ __launch_bounds__(512, 4) void sort_reduce_finalize(
    const float* __restrict__ feat, const __half* __restrict__ FWh,
    const __half* __restrict__ WT, const float* __restrict__ norm,
    const float* __restrict__ s1, const float* __restrict__ s2,
    const int* __restrict__ gcur, const unsigned* __restrict__ ebuf,
    float* __restrict__ out, int C, int N) {
  __shared__ uint2 sdata[CAPB];         // 20.0 KB
  __shared__ float Yl[NB * D];          // 16 KB
  __shared__ float s2l[NB];
  __shared__ int hist[NB];
  __shared__ int starts[NB + 1];
  __shared__ int roff[NB];

  const int tid  = threadIdx.x;
  const int lane = tid & 63;
  const int w    = tid >> 6;           // 0..7
  const int b    = blockIdx.x;
  const int n0   = b << SHIFT;
  const int beg  = b * CAPB;
  const int cnt  = min(gcur[b], CAPB);

  if (tid < NB) {
    hist[tid] = 0;
    const int n = n0 + tid;
    s2l[tid] = (n < N) ? s2[n] : 0.0f;
  }
  __syncthreads();

  // ---- phase 1: stage + hist + thread-parallel attention + scan + place ----
  unsigned ereg[5];                     // ceil(CAPB/512) = 5
  float    areg[5];
  #pragma unroll
  for (int k = 0; k < 5; ++k) {
    const int i = tid + (k << 9);
    if (i < cnt) {
      ereg[k] = ebuf[beg + i];
      atomicAdd(&hist[ereg[k] >> 26], 1);
    }
  }
  #pragma unroll
  for (int k = 0; k < 5; ++k) {         // att: 64 edges per wave-instr
    const int i = tid + (k << 9);
    if (i < cnt) {
      const unsigned src = ereg[k] & 0x03FFFFFFu;
      const float v = s1[src] + s2l[ereg[k] >> 26];
      areg[k] = 1.0f / (1.0f + __expf(-fmaxf(v, 0.0f)));
    }
  }
  __syncthreads();
  if (tid < 64) {                       // wave 0: scan 64 counters
    const int v = hist[tid];
    int incl = v;
    #pragma unroll
    for (int off = 1; off < 64; off <<= 1) {
      const int o = __shfl_up(incl, off, 64);
      if (tid >= off) incl += o;
    }
    starts[tid] = incl - v;
    roff[tid]   = incl - v;
    if (tid == 63) starts[64] = incl;
  }
  __syncthreads();
  #pragma unroll
  for (int k = 0; k < 5; ++k) {
    const int i = tid + (k << 9);
    if (i < cnt) {
      const int pos = atomicAdd(&roff[ereg[k] >> 26], 1);
      sdata[pos] = make_uint2(ereg[k], __float_as_uint(areg[k]));
    }
  }

  // ---- phase 2: Y = feat @ (loop|evolve) via MFMA -> Yl ----
  {
    const int r = lane & 15, g = lane >> 4;
    const bool evw = (w >= 4);
    const int mt = w & 3;              // row tile: rows mt*16 .. mt*16+15
    bool skip = false;
    if (evw) {                         // skip when all 16 rows have messages
      const int rr0 = mt * 16;
      const int flag = (lane < 16)
          ? ((starts[rr0 + lane + 1] > starts[rr0 + lane]) ? 1 : 0) : 1;
      skip = (__ballot(flag == 0) == 0ULL);
    }
    if (!skip) {
      half8 ah[2], al[2];
      const int arow = n0 + mt * 16 + r;
      #pragma unroll
      for (int ks = 0; ks < 2; ++ks) {
        float v[8];
        if (arow < N) {
          const float4 u0 = *(const float4*)&feat[(size_t)arow * D + ks * 32 + g * 8];
          const float4 u1 = *(const float4*)&feat[(size_t)arow * D + ks * 32 + g * 8 + 4];
          v[0] = u0.x; v[1] = u0.y; v[2] = u0.z; v[3] = u0.w;
          v[4] = u1.x; v[5] = u1.y; v[6] = u1.z; v[7] = u1.w;
        } else {
          #pragma unroll
          for (int q = 0; q < 8; ++q) v[q] = 0.0f;
        }
        #pragma unroll
        for (int q = 0; q < 8; ++q) {
          const _Float16 hh = (_Float16)v[q];
          ah[ks][q] = hh;
          al[ks][q] = (_Float16)(v[q] - (float)hh);
        }
      }
      const int wrow0 = evw ? 128 : 64;  // WT rows: 64=loop, 128=evolve
      #pragma unroll
      for (int nt = 0; nt < 4; ++nt) {
        f32x4 a0 = {0.0f, 0.0f, 0.0f, 0.0f};
        #pragma unroll
        for (int ks = 0; ks < 2; ++ks) {
          const half8 bw = *reinterpret_cast<const half8*>(
              WT + (size_t)(wrow0 + nt * 16 + r) * 64 + ks * 32 + g * 8);
          a0 = __builtin_amdgcn_mfma_f32_16x16x32_f16(ah[ks], bw, a0, 0, 0, 0);
          a0 = __builtin_amdgcn_mfma_f32_16x16x32_f16(al[ks], bw, a0, 0, 0, 0);
        }
        #pragma unroll
        for (int q = 0; q < 4; ++q) {
          const int gr = mt * 16 + g * 4 + q;     // C/D row
          const bool hm = starts[gr + 1] > starts[gr];
          if (evw != hm) Yl[gr * D + nt * 16 + r] = a0[q];  // owner writes
        }
      }
    }
  }
  __syncthreads();   // sdata sorted (with att), Yl ready

  // ---- phase 3: quad-gather reduce (4 edges per instruction) ----
  const int qe = lane >> 4;            // edge slot 0..3
  const int qc = lane & 15;            // col group: cols 4qc .. 4qc+3
  float agg[NPW];
  #pragma unroll
  for (int j = 0; j < NPW; ++j) agg[j] = 0.0f;
  for (int j = 0; j < NPW; ++j) {
    const int dl = w * NPW + j;
    const int n  = n0 + dl;
    if (n >= N) break;                 // wave-uniform
    const int rb = __builtin_amdgcn_readfirstlane(starts[dl]);
    const int re = __builtin_amdgcn_readfirstlane(starts[dl + 1]);
    float sa = 0.0f, sb = 0.0f, sc = 0.0f, sd = 0.0f;  // cols 4qc..4qc+3
    int p = rb;
    for (; p + 16 <= re; p += 16) {    // 4 quads = 16 edges in flight
      uint2 ee[4];
      #pragma unroll
      for (int q = 0; q < 4; ++q) ee[q] = sdata[p + 4 * q + qe];
      #pragma unroll
      for (int q = 0; q < 4; ++q) {
        const uint2 vv = *(const uint2*)(
            FWh + (((size_t)(ee[q].x & 0x03FFFFFFu)) << 6) + (qc << 2));
        const float a = __uint_as_float(ee[q].y);
        const float2 f0 = __half22float2(*(const __half2*)&vv.x);
        const float2 f1 = __half22float2(*(const __half2*)&vv.y);
        sa += a * f0.x; sb += a * f0.y; sc += a * f1.x; sd += a * f1.y;
      }
    }
    for (; p < re; p += 4) {           // predicated tail
      const int idx = p + qe;
      const bool vld = idx < re;
      const uint2 e = sdata[vld ? idx : rb];
      const uint2 vv = *(const uint2*)(
          FWh + (((size_t)(e.x & 0x03FFFFFFu)) << 6) + (qc << 2));
      const float a = vld ? __uint_as_float(e.y) : 0.0f;
      const float2 f0 = __half22float2(*(const __half2*)&vv.x);
      const float2 f1 = __half22float2(*(const __half2*)&vv.y);
      sa += a * f0.x; sb += a * f0.y; sc += a * f1.x; sd += a * f1.y;
    }
    // combine edge slots (lanes differing in bits 4,5)
    sa += __shfl_xor(sa, 16, 64); sa += __shfl_xor(sa, 32, 64);
    sb += __shfl_xor(sb, 16, 64); sb += __shfl_xor(sb, 32, 64);
    sc += __shfl_xor(sc, 16, 64); sc += __shfl_xor(sc, 32, 64);
    sd += __shfl_xor(sd, 16, 64); sd += __shfl_xor(sd, 32, 64);
    // redistribute: lane c wants col c = 4*(c>>2) + (c&3); source lane c>>2
    const float t0 = __shfl(sa, lane >> 2, 64);
    const float t1 = __shfl(sb, lane >> 2, 64);
    const float t2 = __shfl(sc, lane >> 2, 64);
    const float t3 = __shfl(sd, lane >> 2, 64);
    const int sel = lane & 3;
    agg[j] = (sel == 0) ? t0 : (sel == 1) ? t1 : (sel == 2) ? t2 : t3;
  }

  // ---- phase 4: finalize (same (w,j,lane) map as phase 3) ----
  for (int j = 0; j < NPW; ++j) {
    const int dl = w * NPW + j;
    const int n  = n0 + dl;
    if (n >= N) break;
    const bool hm = starts[dl + 1] > starts[dl];   // wave-uniform
    const float nr = norm[n];
    const float base = hm ? agg[j] : feat[(size_t)n * D + lane];
    out[(size_t)n * D + lane] = tanhf(base * nr + Yl[dl * D + lane]);
  }
}

extern "C" void kernel_launch(void* const* d_in, const int* in_sizes, int n_in,
                              void* d_out, int out_size, void* d_ws, size_t ws_size,
                              hipStream_t stream) {
  const float* feat     = (const float*)d_in[0];
  const float* norm     = (const float*)d_in[1];
  const int*   esrc     = (const int*)d_in[2];
  const int*   edst     = (const int*)d_in[3];
  // d_in[4] = etype: no-op permutation per the reference
  const float* W_rel    = (const float*)d_in[5];
  const float* lin_w    = (const float*)d_in[6];
  const float* lin_b    = (const float*)d_in[7];
  const float* loop_w   = (const float*)d_in[8];
  const float* evolve_w = (const float*)d_in[9];
  float* out = (float*)d_out;

  const int N = in_sizes[1];   // norm is [N]   (N <= 65536: src fits 26 bits)
  const int E = in_sizes[2];   // edge_src is [E]
  const int C = (N + NB - 1) >> SHIFT;   // 782 for N=50000

  // layout: s1|s2 | gcur | WT | FWh | ebuf[C*CAPB] 4B  (~15 MB; ws is 256 MiB)
  char* p = (char*)d_ws;
  float*    s1   = (float*)p;    p += (size_t)N * sizeof(float);
  float*    s2   = (float*)p;    p += (size_t)N * sizeof(float);
  int*      gcur = (int*)p;      p += (size_t)2048 * sizeof(int);
  __half*   WT   = (__half*)p;   p += (size_t)192 * 64 * sizeof(__half);
  __half*   FWh  = (__half*)p;   p += (size_t)N * D * sizeof(__half);
  unsigned* ebuf = (unsigned*)p;

  const int E4 = E >> 2;
  const int eblocks = (E4 + 511) / 512;            // 782 for E=1.6M

  hipMemsetAsync(gcur, 0, (size_t)C * sizeof(int), stream);
  pre_scatter<<<eblocks, 512, 0, stream>>>(feat, W_rel, lin_w, lin_b,
                                           loop_w, evolve_w, esrc, edst,
                                           s1, s2, FWh, WT, gcur, ebuf,
                                           N, E, C);
  sort_reduce_finalize<<<C, 512, 0, stream>>>(feat, FWh, WT, norm, s1, s2,
                                              gcur, ebuf, out, C, N);
}